// Round 3
// baseline (6729.066 us; speedup 1.0000x reference)
//
#include <hip/hip_runtime.h>

#define T_LEN 3000
#define BATCH 64
#define G4 100   // 4*H, H=25

// ---------------------------------------------------------------------------
// GEMM: xg[dir][t][b][j] = (b_ih+b_hh)[dir][j] + sum_k in_row(t,b)[k]*w_ih[dir][j][k]
// MODE 0: input is x with layout (B,T,F); MODE 1: input layout (T,B,K)
// grid: (T_LEN*BATCH/64, 2), block: 256 (4 waves; wave w owns cols [25w,25w+25))
// ---------------------------------------------------------------------------
template <int MODE>
__global__ __launch_bounds__(256) void gemm_xg(
    const float* __restrict__ in, const float* __restrict__ w_ih,
    const float* __restrict__ b_ih, const float* __restrict__ b_hh,
    float* __restrict__ xg, int K) {
  __shared__ __align__(16) float lds_x[64][33];   // pad 33: (lane+k)%32 -> 2-way max (free)
  __shared__ __align__(16) float lds_w[100][32];  // rows 128B-aligned for float4 reads

  const int tid = threadIdx.x;
  const int dir = blockIdx.y;
  const int r0 = blockIdx.x * 64;
  const int lane = tid & 63;
  const int wv = tid >> 6;
  const int c0 = wv * 25;
  const float* wbase = w_ih + (size_t)dir * G4 * K;

  float acc[25];
#pragma unroll
  for (int c = 0; c < 25; ++c)
    acc[c] = b_ih[dir * G4 + c0 + c] + b_hh[dir * G4 + c0 + c];

  for (int k0 = 0; k0 < K; k0 += 32) {
    const int kw = min(32, K - k0);
#pragma unroll
    for (int i = 0; i < 8; ++i) {
      int e = tid + i * 256;
      int rr = e >> 5, kk = e & 31;
      int grow = r0 + rr;
      const float* rp;
      if (MODE == 0) {
        int tt = grow >> 6, bb = grow & 63;   // row = t*64 + b
        rp = in + ((size_t)bb * T_LEN + tt) * K;
      } else {
        rp = in + (size_t)grow * K;
      }
      lds_x[rr][kk] = (kk < kw) ? rp[k0 + kk] : 0.f;
    }
#pragma unroll
    for (int i = 0; i < 13; ++i) {
      int e = tid + i * 256;
      if (e < 3200) {
        int j = e >> 5, kk = e & 31;
        lds_w[j][kk] = (kk < kw) ? wbase[(size_t)j * K + k0 + kk] : 0.f;
      }
    }
    __syncthreads();
#pragma unroll 2
    for (int k4 = 0; k4 < 8; ++k4) {
      float xv0 = lds_x[lane][k4 * 4 + 0];
      float xv1 = lds_x[lane][k4 * 4 + 1];
      float xv2 = lds_x[lane][k4 * 4 + 2];
      float xv3 = lds_x[lane][k4 * 4 + 3];
#pragma unroll
      for (int c = 0; c < 25; ++c) {
        float4 w4 = *(const float4*)&lds_w[c0 + c][k4 * 4];  // wave-uniform broadcast
        acc[c] = fmaf(xv0, w4.x, acc[c]);
        acc[c] = fmaf(xv1, w4.y, acc[c]);
        acc[c] = fmaf(xv2, w4.z, acc[c]);
        acc[c] = fmaf(xv3, w4.w, acc[c]);
      }
    }
    __syncthreads();
  }
  const int row = r0 + lane;
  float* orow = xg + ((size_t)dir * T_LEN * BATCH + row) * G4 + c0;
#pragma unroll
  for (int c = 0; c < 25; ++c) orow[c] = acc[c];
}

// ---------------------------------------------------------------------------
// Fast activations (v_rcp_f32, 1 ulp — absmax margin is 6x).
// ---------------------------------------------------------------------------
__device__ __forceinline__ float frcp(float x) { return __builtin_amdgcn_rcpf(x); }
__device__ __forceinline__ float sigm(float x) { return frcp(1.f + __expf(-x)); }
__device__ __forceinline__ float tanh_f(float x) { return 1.f - 2.f * frcp(__expf(2.f * x) + 1.f); }

// ---------------------------------------------------------------------------
// LSTM scan v3: one wave = TWO sequences (b0,b0+1) of the same direction
// (shared weights). Gate split across lane halves: lane n in [0,25) owns
// (i_n, g_n); lane 32+n owns (f_n, o_n) + cell c_n.
//  - weights pinned in VGPRs via asm keep-alive (blocks remat-into-loop)
//  - u = i*g shipped lane n -> lane 32+n via v_permlane32_swap (VALU, ~4cyc;
//    semantics disambiguated once with a lane-id tag swap)
//  - h broadcast via 25 independent ds_bpermute (no LDS write->read hazard);
//    issued at end of each seq phase, consumed a full phase later
//  - depth-4 xg prefetch
// grid = 64 blocks x 64 threads.
// ---------------------------------------------------------------------------
typedef int v2i __attribute__((ext_vector_type(2)));

__global__ __launch_bounds__(64, 1) void lstm_scan(
    const float* __restrict__ xg,    // [2][T][B][100]
    const float* __restrict__ w_hh,  // [2][100][25]
    float* __restrict__ hout) {      // [T][B][50]
  const int dir = blockIdx.x & 1;
  const int b0 = (blockIdx.x >> 1) * 2;
  const int lane = threadIdx.x;
  const bool isC = lane >= 32;
  const int nn = lane & 31;
  const int n = (nn < 25) ? nn : 0;          // clamp idle lanes
  const bool writer = isC && (nn < 25);
  const int qA = n + (isC ? 25 : 0);         // gate row: i_n or f_n
  const int qB = qA + 50;                    // gate row: g_n or o_n

  // one-time permlane32_swap semantics probe: which ret element carries the
  // partner (lane^32) half? Loop-invariant per-lane bool -> one cndmask/step.
  v2i tr = __builtin_amdgcn_permlane32_swap(lane, lane, 0, 0);
  const bool pick0 = (tr[0] == (lane ^ 32));

  // per-lane weights, pinned register-resident
  const float* wb = w_hh + (size_t)dir * G4 * 25;
  float wA[25], wB[25];
#pragma unroll
  for (int k = 0; k < 25; ++k) {
    wA[k] = wb[qA * 25 + k];
    wB[k] = wb[qB * 25 + k];
  }
#pragma unroll
  for (int k = 0; k < 25; ++k) {
    asm volatile("" : "+v"(wA[k]));
    asm volatile("" : "+v"(wB[k]));
  }

  float h0[25], h1[25], c0 = 0.f, c1 = 0.f;
#pragma unroll
  for (int k = 0; k < 25; ++k) { h0[k] = 0.f; h1[k] = 0.f; }

  const float* xbase0 = xg + (size_t)dir * T_LEN * BATCH * G4 + (size_t)b0 * G4;
  const float* xbase1 = xbase0 + G4;

  auto xrow = [&](const float* xbase, int s) -> const float* {
    int ss = min(s, T_LEN - 1);
    int tt = dir ? (T_LEN - 1 - ss) : ss;
    return xbase + (size_t)tt * (BATCH * G4);
  };

  // one full step for one sequence
  auto step = [&](float (&h)[25], float& cc, const float* xbase, int bglob,
                  float (&pf)[2], int s) {
    float pA = pf[0], pB = pf[1];
    {  // prefetch 4 steps ahead (slot rotation via unroll-by-4)
      const float* nr = xrow(xbase, s + 4);
      pf[0] = nr[qA];
      pf[1] = nr[qB];
    }
#pragma unroll
    for (int k = 0; k < 25; ++k) {
      pA = fmaf(wA[k], h[k], pA);
      pB = fmaf(wB[k], h[k], pB);
    }
    float aA = sigm(pA);                       // sigm(i) | sigm(f)
    float xbv = isC ? pB : (pB + pB);
    float sb = sigm(xbv);
    float bg = isC ? sb : fmaf(2.f, sb, -1.f); // sigm(o) | tanh(g)
    float u = aA * bg;                         // i*g on A-lanes
    int ui = __float_as_int(u);
    v2i r = __builtin_amdgcn_permlane32_swap(ui, ui, 0, 0);
    float uu = __int_as_float(pick0 ? r[0] : r[1]);  // u_n on lane 32+n
    cc = fmaf(aA, cc, uu);                     // f*c + i*g (C-lanes)
    float hn = bg * tanh_f(cc);                // o*tanh(c) (C-lanes)
    if (writer) {
      int tt = dir ? (T_LEN - 1 - s) : s;
      hout[((size_t)tt * BATCH + bglob) * 50 + dir * 25 + n] = hn;
    }
    // broadcast h for next step: 25 independent bpermutes, consumed next phase
#pragma unroll
    for (int k = 0; k < 25; ++k) h[k] = __shfl(hn, 32 + k);
  };

  float pf0[4][2], pf1[4][2];
#pragma unroll
  for (int d = 0; d < 4; ++d) {
    const float* r0p = xrow(xbase0, d);
    const float* r1p = xrow(xbase1, d);
    pf0[d][0] = r0p[qA]; pf0[d][1] = r0p[qB];
    pf1[d][0] = r1p[qA]; pf1[d][1] = r1p[qB];
  }

  for (int s = 0; s < T_LEN; s += 4) {
#pragma unroll
    for (int d = 0; d < 4; ++d) {
      step(h0, c0, xbase0, b0,     pf0[d], s + d);
      step(h1, c1, xbase1, b0 + 1, pf1[d], s + d);
    }
  }
}

// ---------------------------------------------------------------------------
// FC: out[b][t][m] = sum_j h[t][b][j] * fc_w[m][j] + fc_b[m]
// ---------------------------------------------------------------------------
__global__ __launch_bounds__(256) void fc_kernel(
    const float* __restrict__ h, const float* __restrict__ fc_w,
    const float* __restrict__ fc_b, float* __restrict__ out) {
  int row = blockIdx.x * 256 + threadIdx.x;  // row = t*B + b
  if (row >= T_LEN * BATCH) return;
  int t = row >> 6, b = row & 63;
  const float* hr = h + (size_t)row * 50;
  float a0 = fc_b[0], a1 = fc_b[1], a2 = fc_b[2];
#pragma unroll
  for (int j = 0; j < 50; ++j) {
    float v = hr[j];
    a0 = fmaf(v, fc_w[j], a0);
    a1 = fmaf(v, fc_w[50 + j], a1);
    a2 = fmaf(v, fc_w[100 + j], a2);
  }
  float* op = out + ((size_t)b * T_LEN + t) * 3;
  op[0] = a0; op[1] = a1; op[2] = a2;
}

// ---------------------------------------------------------------------------
extern "C" void kernel_launch(void* const* d_in, const int* in_sizes, int n_in,
                              void* d_out, int out_size, void* d_ws, size_t ws_size,
                              hipStream_t stream) {
  const float* x = (const float*)d_in[0];
  const float* w_ih[3] = {(const float*)d_in[1], (const float*)d_in[5], (const float*)d_in[9]};
  const float* w_hh[3] = {(const float*)d_in[2], (const float*)d_in[6], (const float*)d_in[10]};
  const float* b_ih[3] = {(const float*)d_in[3], (const float*)d_in[7], (const float*)d_in[11]};
  const float* b_hh[3] = {(const float*)d_in[4], (const float*)d_in[8], (const float*)d_in[12]};
  const float* fc_w = (const float*)d_in[13];
  const float* fc_b = (const float*)d_in[14];
  float* out = (float*)d_out;

  float* xg = (float*)d_ws;                                 // 2*T*B*100 fp32 = 153.6 MB
  float* hA = xg + (size_t)2 * T_LEN * BATCH * G4;          // T*B*50 = 38.4 MB
  float* hB = hA + (size_t)T_LEN * BATCH * 50;              // T*B*50 = 38.4 MB

  dim3 gg(T_LEN * BATCH / 64, 2), gb(256);

  // layer 0
  hipLaunchKernelGGL((gemm_xg<0>), gg, gb, 0, stream, x, w_ih[0], b_ih[0], b_hh[0], xg, 314);
  hipLaunchKernelGGL(lstm_scan, dim3(BATCH), dim3(64), 0, stream, xg, w_hh[0], hA);
  // layer 1
  hipLaunchKernelGGL((gemm_xg<1>), gg, gb, 0, stream, hA, w_ih[1], b_ih[1], b_hh[1], xg, 50);
  hipLaunchKernelGGL(lstm_scan, dim3(BATCH), dim3(64), 0, stream, xg, w_hh[1], hB);
  // layer 2
  hipLaunchKernelGGL((gemm_xg<1>), gg, gb, 0, stream, hB, w_ih[2], b_ih[2], b_hh[2], xg, 50);
  hipLaunchKernelGGL(lstm_scan, dim3(BATCH), dim3(64), 0, stream, xg, w_hh[2], hA);
  // fc
  hipLaunchKernelGGL(fc_kernel, dim3(T_LEN * BATCH / 256), dim3(256), 0, stream, hA, fc_w, fc_b, out);
}

// Round 4
// 4854.350 us; speedup vs baseline: 1.3862x; 1.3862x over previous
//
#include <hip/hip_runtime.h>

#define T_LEN 3000
#define BATCH 64
#define G4 100   // 4*H, H=25

// ---------------------------------------------------------------------------
// GEMM: xg[dir][t][b][j] = (b_ih+b_hh)[dir][j] + sum_k in_row(t,b)[k]*w_ih[dir][j][k]
// MODE 0: input is x with layout (B,T,F); MODE 1: input layout (T,B,K)
// grid: (T_LEN*BATCH/64, 2), block: 256 (4 waves; wave w owns cols [25w,25w+25))
// ---------------------------------------------------------------------------
template <int MODE>
__global__ __launch_bounds__(256) void gemm_xg(
    const float* __restrict__ in, const float* __restrict__ w_ih,
    const float* __restrict__ b_ih, const float* __restrict__ b_hh,
    float* __restrict__ xg, int K) {
  __shared__ __align__(16) float lds_x[64][33];   // pad 33: (lane+k)%32 -> 2-way max (free)
  __shared__ __align__(16) float lds_w[100][32];  // rows 128B-aligned for float4 reads

  const int tid = threadIdx.x;
  const int dir = blockIdx.y;
  const int r0 = blockIdx.x * 64;
  const int lane = tid & 63;
  const int wv = tid >> 6;
  const int c0 = wv * 25;
  const float* wbase = w_ih + (size_t)dir * G4 * K;

  float acc[25];
#pragma unroll
  for (int c = 0; c < 25; ++c)
    acc[c] = b_ih[dir * G4 + c0 + c] + b_hh[dir * G4 + c0 + c];

  for (int k0 = 0; k0 < K; k0 += 32) {
    const int kw = min(32, K - k0);
#pragma unroll
    for (int i = 0; i < 8; ++i) {
      int e = tid + i * 256;
      int rr = e >> 5, kk = e & 31;
      int grow = r0 + rr;
      const float* rp;
      if (MODE == 0) {
        int tt = grow >> 6, bb = grow & 63;   // row = t*64 + b
        rp = in + ((size_t)bb * T_LEN + tt) * K;
      } else {
        rp = in + (size_t)grow * K;
      }
      lds_x[rr][kk] = (kk < kw) ? rp[k0 + kk] : 0.f;
    }
#pragma unroll
    for (int i = 0; i < 13; ++i) {
      int e = tid + i * 256;
      if (e < 3200) {
        int j = e >> 5, kk = e & 31;
        lds_w[j][kk] = (kk < kw) ? wbase[(size_t)j * K + k0 + kk] : 0.f;
      }
    }
    __syncthreads();
#pragma unroll 2
    for (int k4 = 0; k4 < 8; ++k4) {
      float xv0 = lds_x[lane][k4 * 4 + 0];
      float xv1 = lds_x[lane][k4 * 4 + 1];
      float xv2 = lds_x[lane][k4 * 4 + 2];
      float xv3 = lds_x[lane][k4 * 4 + 3];
#pragma unroll
      for (int c = 0; c < 25; ++c) {
        float4 w4 = *(const float4*)&lds_w[c0 + c][k4 * 4];  // wave-uniform broadcast
        acc[c] = fmaf(xv0, w4.x, acc[c]);
        acc[c] = fmaf(xv1, w4.y, acc[c]);
        acc[c] = fmaf(xv2, w4.z, acc[c]);
        acc[c] = fmaf(xv3, w4.w, acc[c]);
      }
    }
    __syncthreads();
  }
  const int row = r0 + lane;
  float* orow = xg + ((size_t)dir * T_LEN * BATCH + row) * G4 + c0;
#pragma unroll
  for (int c = 0; c < 25; ++c) orow[c] = acc[c];
}

// ---------------------------------------------------------------------------
// Fast activations (v_rcp_f32, 1 ulp — absmax margin is 6x).
// ---------------------------------------------------------------------------
__device__ __forceinline__ float frcp(float x) { return __builtin_amdgcn_rcpf(x); }
__device__ __forceinline__ float sigm(float x) { return frcp(1.f + __expf(-x)); }
__device__ __forceinline__ float tanh_f(float x) { return 1.f - 2.f * frcp(__expf(2.f * x) + 1.f); }

// ---------------------------------------------------------------------------
// LSTM scan v4: one wave per (b,dir), 128 blocks. Gate split across halves:
// lane n in [0,25) owns (i_n, g_n); lane 32+n owns (f_n, o_n) + cell c_n.
// Key change vs v2/v3: h lives in 25 SGPRs via v_readlane (VALU pipe),
// NO LDS traffic anywhere in the step. u = i*g crosses via permlane32_swap
// (VALU). Weights and prefetch values pinned in VGPRs with empty asm to
// block rematerialization-into-loop (the v2/v3 failure mode).
// ---------------------------------------------------------------------------
typedef int v2i __attribute__((ext_vector_type(2)));

__global__ __launch_bounds__(64, 1) void lstm_scan(
    const float* __restrict__ xg,    // [2][T][B][100]
    const float* __restrict__ w_hh,  // [2][100][25]
    float* __restrict__ hout) {      // [T][B][50]
  const int dir = blockIdx.x & 1;
  const int b = blockIdx.x >> 1;
  const int lane = threadIdx.x;
  const bool isC = lane >= 32;
  const int nn = lane & 31;
  const int n = (nn < 25) ? nn : 0;          // clamp idle lanes
  const bool writer = isC && (nn < 25);
  const int qA = n + (isC ? 25 : 0);         // gate row: i_n or f_n
  const int qB = qA + 50;                    // gate row: g_n or o_n

  // one-time permlane32_swap semantics probe (loop-invariant -> 1 cndmask/step)
  v2i tr = __builtin_amdgcn_permlane32_swap(lane, lane, 0, 0);
  const bool pick0 = (tr[0] == (lane ^ 32));

  // per-lane weights, pinned register-resident
  const float* wb = w_hh + (size_t)dir * G4 * 25;
  float wA[25], wB[25];
#pragma unroll
  for (int k = 0; k < 25; ++k) {
    wA[k] = wb[qA * 25 + k];
    wB[k] = wb[qB * 25 + k];
  }
#pragma unroll
  for (int k = 0; k < 25; ++k) {
    asm("" : "+v"(wA[k]));
    asm("" : "+v"(wB[k]));
  }

  // h state: wave-uniform scalars (readlane results) — SGPR-resident
  float hs[25];
#pragma unroll
  for (int k = 0; k < 25; ++k) hs[k] = 0.f;
  float c = 0.f;

  const float* xbase = xg + (size_t)dir * T_LEN * BATCH * G4 + (size_t)b * G4;
  auto xrow = [&](int s) -> const float* {
    int ss = min(s, T_LEN - 1);
    int tt = dir ? (T_LEN - 1 - ss) : ss;
    return xbase + (size_t)tt * (BATCH * G4);
  };

  auto step = [&](float (&pf)[2], int s) {
    float pA = pf[0], pB = pf[1];
    {  // prefetch 4 steps ahead; pin so it can't be rematerialized into use
      const float* nr = xrow(s + 4);
      pf[0] = nr[qA];
      pf[1] = nr[qB];
      asm("" : "+v"(pf[0]));
      asm("" : "+v"(pf[1]));
    }
#pragma unroll
    for (int k = 0; k < 25; ++k) {
      pA = fmaf(wA[k], hs[k], pA);
      pB = fmaf(wB[k], hs[k], pB);
    }
    float aA = sigm(pA);                       // sigm(i) | sigm(f)
    float xbv = isC ? pB : (pB + pB);
    float sb = sigm(xbv);
    float bg = isC ? sb : fmaf(2.f, sb, -1.f); // sigm(o) | tanh(g)
    float u = aA * bg;                         // i*g on A-lanes
    int ui = __float_as_int(u);
    v2i r = __builtin_amdgcn_permlane32_swap(ui, ui, 0, 0);
    float uu = __int_as_float(pick0 ? r[0] : r[1]);  // u_n lands on lane 32+n
    c = fmaf(aA, c, uu);                       // f*c + i*g (C-lanes)
    float hn = bg * tanh_f(c);                 // o*tanh(c) (C-lanes)
    if (writer) {
      int tt = dir ? (T_LEN - 1 - s) : s;
      hout[((size_t)tt * BATCH + b) * 50 + dir * 25 + n] = hn;
    }
    // h broadcast: 25 independent readlanes (VALU), no LDS pipe
    int hi = __float_as_int(hn);
#pragma unroll
    for (int k = 0; k < 25; ++k)
      hs[k] = __int_as_float(__builtin_amdgcn_readlane(hi, 32 + k));
  };

  float pf[4][2];
#pragma unroll
  for (int d = 0; d < 4; ++d) {
    const float* rp = xrow(d);
    pf[d][0] = rp[qA];
    pf[d][1] = rp[qB];
  }

  for (int s = 0; s < T_LEN; s += 4) {
#pragma unroll
    for (int d = 0; d < 4; ++d) step(pf[d], s + d);
  }
}

// ---------------------------------------------------------------------------
// FC: out[b][t][m] = sum_j h[t][b][j] * fc_w[m][j] + fc_b[m]
// ---------------------------------------------------------------------------
__global__ __launch_bounds__(256) void fc_kernel(
    const float* __restrict__ h, const float* __restrict__ fc_w,
    const float* __restrict__ fc_b, float* __restrict__ out) {
  int row = blockIdx.x * 256 + threadIdx.x;  // row = t*B + b
  if (row >= T_LEN * BATCH) return;
  int t = row >> 6, b = row & 63;
  const float* hr = h + (size_t)row * 50;
  float a0 = fc_b[0], a1 = fc_b[1], a2 = fc_b[2];
#pragma unroll
  for (int j = 0; j < 50; ++j) {
    float v = hr[j];
    a0 = fmaf(v, fc_w[j], a0);
    a1 = fmaf(v, fc_w[50 + j], a1);
    a2 = fmaf(v, fc_w[100 + j], a2);
  }
  float* op = out + ((size_t)b * T_LEN + t) * 3;
  op[0] = a0; op[1] = a1; op[2] = a2;
}

// ---------------------------------------------------------------------------
extern "C" void kernel_launch(void* const* d_in, const int* in_sizes, int n_in,
                              void* d_out, int out_size, void* d_ws, size_t ws_size,
                              hipStream_t stream) {
  const float* x = (const float*)d_in[0];
  const float* w_ih[3] = {(const float*)d_in[1], (const float*)d_in[5], (const float*)d_in[9]};
  const float* w_hh[3] = {(const float*)d_in[2], (const float*)d_in[6], (const float*)d_in[10]};
  const float* b_ih[3] = {(const float*)d_in[3], (const float*)d_in[7], (const float*)d_in[11]};
  const float* b_hh[3] = {(const float*)d_in[4], (const float*)d_in[8], (const float*)d_in[12]};
  const float* fc_w = (const float*)d_in[13];
  const float* fc_b = (const float*)d_in[14];
  float* out = (float*)d_out;

  float* xg = (float*)d_ws;                                 // 2*T*B*100 fp32 = 153.6 MB
  float* hA = xg + (size_t)2 * T_LEN * BATCH * G4;          // T*B*50 = 38.4 MB
  float* hB = hA + (size_t)T_LEN * BATCH * 50;              // T*B*50 = 38.4 MB

  dim3 gg(T_LEN * BATCH / 64, 2), gb(256);

  // layer 0
  hipLaunchKernelGGL((gemm_xg<0>), gg, gb, 0, stream, x, w_ih[0], b_ih[0], b_hh[0], xg, 314);
  hipLaunchKernelGGL(lstm_scan, dim3(2 * BATCH), dim3(64), 0, stream, xg, w_hh[0], hA);
  // layer 1
  hipLaunchKernelGGL((gemm_xg<1>), gg, gb, 0, stream, hA, w_ih[1], b_ih[1], b_hh[1], xg, 50);
  hipLaunchKernelGGL(lstm_scan, dim3(2 * BATCH), dim3(64), 0, stream, xg, w_hh[1], hB);
  // layer 2
  hipLaunchKernelGGL((gemm_xg<1>), gg, gb, 0, stream, hB, w_ih[2], b_ih[2], b_hh[2], xg, 50);
  hipLaunchKernelGGL(lstm_scan, dim3(2 * BATCH), dim3(64), 0, stream, xg, w_hh[2], hA);
  // fc
  hipLaunchKernelGGL(fc_kernel, dim3(T_LEN * BATCH / 256), dim3(256), 0, stream, hA, fc_w, fc_b, out);
}

// Round 5
// 3229.643 us; speedup vs baseline: 2.0835x; 1.5031x over previous
//
#include <hip/hip_runtime.h>

#define T_LEN 3000
#define BATCH 64
#define G4 100   // 4*H, H=25

// ---------------------------------------------------------------------------
// GEMM: xg[dir][t][b][j] = (b_ih+b_hh)[dir][j] + sum_k in_row(t,b)[k]*w_ih[dir][j][k]
// MODE 0: input is x with layout (B,T,F); MODE 1: input layout (T,B,K)
// ---------------------------------------------------------------------------
template <int MODE>
__global__ __launch_bounds__(256) void gemm_xg(
    const float* __restrict__ in, const float* __restrict__ w_ih,
    const float* __restrict__ b_ih, const float* __restrict__ b_hh,
    float* __restrict__ xg, int K) {
  __shared__ __align__(16) float lds_x[64][33];
  __shared__ __align__(16) float lds_w[100][32];

  const int tid = threadIdx.x;
  const int dir = blockIdx.y;
  const int r0 = blockIdx.x * 64;
  const int lane = tid & 63;
  const int wv = tid >> 6;
  const int c0 = wv * 25;
  const float* wbase = w_ih + (size_t)dir * G4 * K;

  float acc[25];
#pragma unroll
  for (int c = 0; c < 25; ++c)
    acc[c] = b_ih[dir * G4 + c0 + c] + b_hh[dir * G4 + c0 + c];

  for (int k0 = 0; k0 < K; k0 += 32) {
    const int kw = min(32, K - k0);
#pragma unroll
    for (int i = 0; i < 8; ++i) {
      int e = tid + i * 256;
      int rr = e >> 5, kk = e & 31;
      int grow = r0 + rr;
      const float* rp;
      if (MODE == 0) {
        int tt = grow >> 6, bb = grow & 63;   // row = t*64 + b
        rp = in + ((size_t)bb * T_LEN + tt) * K;
      } else {
        rp = in + (size_t)grow * K;
      }
      lds_x[rr][kk] = (kk < kw) ? rp[k0 + kk] : 0.f;
    }
#pragma unroll
    for (int i = 0; i < 13; ++i) {
      int e = tid + i * 256;
      if (e < 3200) {
        int j = e >> 5, kk = e & 31;
        lds_w[j][kk] = (kk < kw) ? wbase[(size_t)j * K + k0 + kk] : 0.f;
      }
    }
    __syncthreads();
#pragma unroll 2
    for (int k4 = 0; k4 < 8; ++k4) {
      float xv0 = lds_x[lane][k4 * 4 + 0];
      float xv1 = lds_x[lane][k4 * 4 + 1];
      float xv2 = lds_x[lane][k4 * 4 + 2];
      float xv3 = lds_x[lane][k4 * 4 + 3];
#pragma unroll
      for (int c = 0; c < 25; ++c) {
        float4 w4 = *(const float4*)&lds_w[c0 + c][k4 * 4];  // wave-uniform broadcast
        acc[c] = fmaf(xv0, w4.x, acc[c]);
        acc[c] = fmaf(xv1, w4.y, acc[c]);
        acc[c] = fmaf(xv2, w4.z, acc[c]);
        acc[c] = fmaf(xv3, w4.w, acc[c]);
      }
    }
    __syncthreads();
  }
  const int row = r0 + lane;
  float* orow = xg + ((size_t)dir * T_LEN * BATCH + row) * G4 + c0;
#pragma unroll
  for (int c = 0; c < 25; ++c) orow[c] = acc[c];
}

// ---------------------------------------------------------------------------
// Fast activations (v_rcp_f32, 1 ulp — absmax margin is 6x).
// ---------------------------------------------------------------------------
__device__ __forceinline__ float frcp(float x) { return __builtin_amdgcn_rcpf(x); }
__device__ __forceinline__ float sigm(float x) { return frcp(1.f + __expf(-x)); }
__device__ __forceinline__ float tanh_f(float x) { return 1.f - 2.f * frcp(__expf(2.f * x) + 1.f); }

// ---------------------------------------------------------------------------
// LSTM scan v5: one wave per (b,dir), 128 blocks.
// Lane n in [0,25): gates (i_n, g_n). Lane 32+n: gates (f_n, o_n) + cell c_n.
// All cross-lane traffic on the VALU pipe:
//   u = i*g      : v_permlane32_swap (~4 cyc)
//   h broadcast  : 25x v_readlane -> SGPRs (interleavable with next dot)
// xg prefetch: 3 chunks x 4 steps in flight (24 VGPR) -> issue-to-use >= 8
// steps (~1600+ cyc) > ~900 cyc HBM latency; straight-line, no per-step clamp.
// Weights pinned with asm VOLATILE (r3-proven; r4's non-volatile pin sank).
// amdgpu_waves_per_eu(1,1): 512-VGPR budget (occupancy is 1 wave/CU anyway).
// ---------------------------------------------------------------------------
typedef int v2i __attribute__((ext_vector_type(2)));

__global__ __launch_bounds__(64)
__attribute__((amdgpu_waves_per_eu(1, 1)))
void lstm_scan(
    const float* __restrict__ xg,    // [2][T][B][100]
    const float* __restrict__ w_hh,  // [2][100][25]
    float* __restrict__ hout) {      // [T][B][50]
  const int dir = blockIdx.x & 1;
  const int b = blockIdx.x >> 1;
  const int lane = threadIdx.x;
  const bool isC = lane >= 32;
  const int nn = lane & 31;
  const int n = (nn < 25) ? nn : 24;         // clamp idle lanes
  const bool writer = isC && (nn < 25);
  const int qA = n + (isC ? 25 : 0);         // gate row: i_n or f_n
  const int qB = qA + 50;                    // gate row: g_n or o_n

  // one-time permlane32_swap semantics probe (loop-invariant -> 1 cndmask/step)
  v2i tr = __builtin_amdgcn_permlane32_swap(lane, lane, 0, 0);
  const bool pick0 = (tr[0] == (lane ^ 32));

  // per-lane weights, pinned register-resident (volatile: cannot sink/remat)
  const float* wb = w_hh + (size_t)dir * G4 * 25;
  float wA[25], wB[25];
#pragma unroll
  for (int k = 0; k < 25; ++k) {
    wA[k] = wb[qA * 25 + k];
    wB[k] = wb[qB * 25 + k];
  }
#pragma unroll
  for (int k = 0; k < 25; ++k) {
    asm volatile("" : "+v"(wA[k]), "+v"(wB[k]));
  }

  // h state: wave-uniform readlane results -> SGPRs
  float hs[25];
#pragma unroll
  for (int k = 0; k < 25; ++k) hs[k] = 0.f;
  float c = 0.f;

  const float* xb = xg + (size_t)dir * T_LEN * BATCH * G4 + (size_t)b * G4;

  auto loadchunk = [&](float (&dst)[4][2], int s0) {
#pragma unroll
    for (int d = 0; d < 4; ++d) {
      int ss = min(s0 + d, T_LEN - 1);
      int t = dir ? (T_LEN - 1 - ss) : ss;
      const float* r = xb + (size_t)t * (BATCH * G4);
      dst[d][0] = r[qA];
      dst[d][1] = r[qB];
    }
  };

  auto step = [&](float (&p)[2], int s) {
    float pA = p[0], pB = p[1];
#pragma unroll
    for (int k = 0; k < 25; ++k) {
      pA = fmaf(wA[k], hs[k], pA);
      pB = fmaf(wB[k], hs[k], pB);
    }
    float aA = sigm(pA);                       // sigm(i) | sigm(f)
    float xbv = isC ? pB : (pB + pB);
    float sb = sigm(xbv);
    float bg = isC ? sb : fmaf(2.f, sb, -1.f); // sigm(o) | tanh(g)
    float u = aA * bg;                         // i*g on A-lanes
    int ui = __float_as_int(u);
    v2i r = __builtin_amdgcn_permlane32_swap(ui, ui, 0, 0);
    float uu = __int_as_float(pick0 ? r[0] : r[1]);  // u_n lands on lane 32+n
    c = fmaf(aA, c, uu);                       // f*c + i*g (C-lanes)
    float hn = bg * tanh_f(c);                 // o*tanh(c) (C-lanes)
    if (writer) {
      int t = dir ? (T_LEN - 1 - s) : s;
      hout[((size_t)t * BATCH + b) * 50 + dir * 25 + n] = hn;
    }
    int hi = __float_as_int(hn);
#pragma unroll
    for (int k = 0; k < 25; ++k)
      hs[k] = __int_as_float(__builtin_amdgcn_readlane(hi, 32 + k));
  };

  float pf[3][4][2];
  loadchunk(pf[0], 0);
  loadchunk(pf[1], 4);
  loadchunk(pf[2], 8);

  for (int s0 = 0; s0 < T_LEN; s0 += 12) {   // 250 iterations
#pragma unroll
    for (int ph = 0; ph < 3; ++ph) {
#pragma unroll
      for (int d = 0; d < 4; ++d) step(pf[ph][d], s0 + ph * 4 + d);
      loadchunk(pf[ph], s0 + 12 + ph * 4);   // refill right after last use
    }
  }
}

// ---------------------------------------------------------------------------
// FC: out[b][t][m] = sum_j h[t][b][j] * fc_w[m][j] + fc_b[m]
// ---------------------------------------------------------------------------
__global__ __launch_bounds__(256) void fc_kernel(
    const float* __restrict__ h, const float* __restrict__ fc_w,
    const float* __restrict__ fc_b, float* __restrict__ out) {
  int row = blockIdx.x * 256 + threadIdx.x;  // row = t*B + b
  if (row >= T_LEN * BATCH) return;
  int t = row >> 6, b = row & 63;
  const float* hr = h + (size_t)row * 50;
  float a0 = fc_b[0], a1 = fc_b[1], a2 = fc_b[2];
#pragma unroll
  for (int j = 0; j < 50; ++j) {
    float v = hr[j];
    a0 = fmaf(v, fc_w[j], a0);
    a1 = fmaf(v, fc_w[50 + j], a1);
    a2 = fmaf(v, fc_w[100 + j], a2);
  }
  float* op = out + ((size_t)b * T_LEN + t) * 3;
  op[0] = a0; op[1] = a1; op[2] = a2;
}

// ---------------------------------------------------------------------------
extern "C" void kernel_launch(void* const* d_in, const int* in_sizes, int n_in,
                              void* d_out, int out_size, void* d_ws, size_t ws_size,
                              hipStream_t stream) {
  const float* x = (const float*)d_in[0];
  const float* w_ih[3] = {(const float*)d_in[1], (const float*)d_in[5], (const float*)d_in[9]};
  const float* w_hh[3] = {(const float*)d_in[2], (const float*)d_in[6], (const float*)d_in[10]};
  const float* b_ih[3] = {(const float*)d_in[3], (const float*)d_in[7], (const float*)d_in[11]};
  const float* b_hh[3] = {(const float*)d_in[4], (const float*)d_in[8], (const float*)d_in[12]};
  const float* fc_w = (const float*)d_in[13];
  const float* fc_b = (const float*)d_in[14];
  float* out = (float*)d_out;

  float* xg = (float*)d_ws;                                 // 2*T*B*100 fp32 = 153.6 MB
  float* hA = xg + (size_t)2 * T_LEN * BATCH * G4;          // T*B*50 = 38.4 MB
  float* hB = hA + (size_t)T_LEN * BATCH * 50;              // T*B*50 = 38.4 MB

  dim3 gg(T_LEN * BATCH / 64, 2), gb(256);

  // layer 0
  hipLaunchKernelGGL((gemm_xg<0>), gg, gb, 0, stream, x, w_ih[0], b_ih[0], b_hh[0], xg, 314);
  hipLaunchKernelGGL(lstm_scan, dim3(2 * BATCH), dim3(64), 0, stream, xg, w_hh[0], hA);
  // layer 1
  hipLaunchKernelGGL((gemm_xg<1>), gg, gb, 0, stream, hA, w_ih[1], b_ih[1], b_hh[1], xg, 50);
  hipLaunchKernelGGL(lstm_scan, dim3(2 * BATCH), dim3(64), 0, stream, xg, w_hh[1], hB);
  // layer 2
  hipLaunchKernelGGL((gemm_xg<1>), gg, gb, 0, stream, hB, w_ih[2], b_ih[2], b_hh[2], xg, 50);
  hipLaunchKernelGGL(lstm_scan, dim3(2 * BATCH), dim3(64), 0, stream, xg, w_hh[2], hA);
  // fc
  hipLaunchKernelGGL(fc_kernel, dim3(T_LEN * BATCH / 256), dim3(256), 0, stream, hA, fc_w, fc_b, out);
}